// Round 11
// baseline (174.576 us; speedup 1.0000x reference)
//
#include <hip/hip_runtime.h>
#include <stdint.h>
#include <stddef.h>
#include <math.h>

#define DEVINL __device__ __forceinline__

typedef __attribute__((ext_vector_type(8))) __bf16 bf16x8;
typedef __attribute__((ext_vector_type(4))) float f32x4;
typedef __attribute__((ext_vector_type(4))) unsigned short us4;
typedef __attribute__((ext_vector_type(8))) unsigned short us8;
typedef __attribute__((ext_vector_type(4))) short short4v;  // K=16 MFMA A/B operand

typedef __attribute__((address_space(1))) unsigned int as1_uint;
typedef __attribute__((address_space(3))) unsigned int as3_uint;

constexpr int SEQ    = 2048;
constexpr int DMODEL = 1024;
constexpr int MTOT   = 4096;    // B*L
constexpr int NQKV   = 3072;
constexpr int DKH    = 64;

// workspace layout (bytes)
constexpr size_t OFF_XBF  = 0;                                      // 8 MiB
constexpr size_t OFF_WQKV = OFF_XBF  + (size_t)MTOT * DMODEL * 2;   // 6 MiB
constexpr size_t OFF_WOUT = OFF_WQKV + (size_t)NQKV * DMODEL * 2;   // 2 MiB
constexpr size_t OFF_Q    = OFF_WOUT + (size_t)DMODEL * DMODEL * 2; // 8 MiB
constexpr size_t OFF_K    = OFF_Q    + (size_t)MTOT * DMODEL * 2;   // 8 MiB
constexpr size_t OFF_VT   = OFF_K    + (size_t)MTOT * DMODEL * 2;   // 8 MiB
constexpr size_t OFF_O    = OFF_VT   + (size_t)MTOT * DMODEL * 2;   // 8 MiB
constexpr size_t OFF_ROPE = OFF_O    + (size_t)MTOT * DMODEL * 2;   // 1 MiB

// Q pre-scale: 1/sqrt(64) * log2(e) -> softmax runs in exp2 domain
constexpr float QSCALE = 0.125f * 1.4426950408889634f;

DEVINL unsigned short f2bf(float f) {
  unsigned int u = __float_as_uint(f);
  u += 0x7fffu + ((u >> 16) & 1u);
  return (unsigned short)(u >> 16);
}

DEVINL void gld_lds16(const unsigned short* g, unsigned short* s) {
  __builtin_amdgcn_global_load_lds((as1_uint*)g, (as3_uint*)s, 16, 0, 0);
}

// ---------------- prep: fp32->bf16 converts + rope table ----------------
__global__ __launch_bounds__(256) void prep_kernel(
    const float* __restrict__ X, const float* __restrict__ Wqkv,
    const float* __restrict__ Wout, const int* __restrict__ pos,
    unsigned short* __restrict__ xbf, unsigned short* __restrict__ wqkvbf,
    unsigned short* __restrict__ woutbf, float2* __restrict__ rope) {
  const int t = blockIdx.x * 256 + threadIdx.x;
  if (t < MTOT * 32) {  // rope table: (m, pair)
    const int m = t >> 5, ip = t & 31;
    const float freq = powf(10000.0f, -(float)(2 * ip) / 64.0f);
    const float ang = (float)pos[m] * freq;
    float sv, cv;
    sincosf(ang, &sv, &cv);
    rope[t] = make_float2(cv, sv);
  }
  const int NX = MTOT * DMODEL, NW1 = NQKV * DMODEL, NW2 = DMODEL * DMODEL;
  const int e = t * 4;
  const float* src;
  unsigned short* dst;
  if (e < NX) { src = X + e; dst = xbf + e; }
  else if (e < NX + NW1) { src = Wqkv + (e - NX); dst = wqkvbf + (e - NX); }
  else if (e < NX + NW1 + NW2) { src = Wout + (e - NX - NW1); dst = woutbf + (e - NX - NW1); }
  else return;
  const float4 v = *(const float4*)src;
  us4 o = { f2bf(v.x), f2bf(v.y), f2bf(v.z), f2bf(v.w) };
  *(us4*)dst = o;
}

// ---------------- GEMM: C[m][n] = sum_k A[m][k]*B[n][k], 128x128 tile ----------------
// MODE 0: A=Xbf, B=Wqkv -> RoPE epilogue, scatter Q (pre-scaled) / K row-major,
//         V transposed per head.
// MODE 1: A=Obf,  B=Wout -> fp32 store to d_out.
template <int MODE>
__global__ __launch_bounds__(256) void gemm_kernel(
    const unsigned short* __restrict__ A, const unsigned short* __restrict__ Bw,
    unsigned short* __restrict__ q_out, unsigned short* __restrict__ k_out,
    unsigned short* __restrict__ vt_out, const float2* __restrict__ rope,
    float* __restrict__ f_out) {
  constexpr int K = DMODEL;  // 1024
  __shared__ __align__(16) unsigned short As[128 * 32];
  __shared__ __align__(16) unsigned short Bs[128 * 32];
  const int tid = threadIdx.x;
  const int l = tid & 63, w = tid >> 6;
  const int g = l >> 4, l15 = l & 15;
  const int m0 = blockIdx.y * 128, n0 = blockIdx.x * 128;
  const int wm = w >> 1, wn = w & 1;

  // staging: per wave 1KiB per instr; lane chunk = base + l*16 bytes in LDS
  const unsigned short* ag = A  + (size_t)(m0 + w * 16 + (l >> 2)) * K + (l & 3) * 8;
  const unsigned short* bg = Bw + (size_t)(n0 + w * 16 + (l >> 2)) * K + (l & 3) * 8;
  unsigned short* as0 = As + w * 512;
  unsigned short* bs0 = Bs + w * 512;

  const f32x4 zf = {0.f, 0.f, 0.f, 0.f};
  f32x4 acc[4][4];
#pragma unroll
  for (int i = 0; i < 4; ++i)
#pragma unroll
    for (int j = 0; j < 4; ++j) acc[i][j] = zf;

  for (int kt = 0; kt < K / 32; ++kt) {
    const unsigned short* a0 = ag + kt * 32;
    const unsigned short* b0 = bg + kt * 32;
    gld_lds16(a0, as0);
    gld_lds16(a0 + (size_t)64 * K, as0 + 2048);
    gld_lds16(b0, bs0);
    gld_lds16(b0 + (size_t)64 * K, bs0 + 2048);
    __syncthreads();
    bf16x8 af[4], bf[4];
#pragma unroll
    for (int i = 0; i < 4; ++i)
      af[i] = *(const bf16x8*)(As + (wm * 64 + i * 16 + l15) * 32 + g * 8);
#pragma unroll
    for (int j = 0; j < 4; ++j)
      bf[j] = *(const bf16x8*)(Bs + (wn * 64 + j * 16 + l15) * 32 + g * 8);
#pragma unroll
    for (int i = 0; i < 4; ++i)
#pragma unroll
      for (int j = 0; j < 4; ++j)
        acc[i][j] = __builtin_amdgcn_mfma_f32_16x16x32_bf16(af[i], bf[j], acc[i][j], 0, 0, 0);
    __syncthreads();
  }

  if constexpr (MODE == 0) {
    const int region = n0 >> 10;  // 0=Q 1=K 2=V (128 | 1024 region boundaries)
    if (region <= 1) {
      unsigned short* outb = (region == 0) ? q_out : k_out;
      const float qs = (region == 0) ? QSCALE : 1.0f;
#pragma unroll
      for (int i = 0; i < 4; ++i) {
        const int mb = m0 + wm * 64 + i * 16 + g * 4;
#pragma unroll
        for (int j = 0; j < 4; ++j) {
          const int n = n0 + wn * 64 + j * 16 + l15;
          const int ncol = n & 1023;
          const int ip = (n & 63) >> 1;
          const float sgn = (n & 1) ? 1.f : -1.f;
#pragma unroll
          for (int r = 0; r < 4; ++r) {
            const int m = mb + r;
            const float v = acc[i][j][r];
            const float p = __shfl_xor(v, 1);  // partner column n^1
            const float2 cs = rope[m * 32 + ip];
            const float o = (v * cs.x + sgn * p * cs.y) * qs;
            outb[(size_t)m * DMODEL + ncol] = f2bf(o);
          }
        }
      }
    } else {  // V -> transposed per head: Vt[(b*1024 + h*64 + d)][l]
#pragma unroll
      for (int i = 0; i < 4; ++i) {
        const int mb = m0 + wm * 64 + i * 16 + g * 4;
        const int b = mb >> 11;
        const int lseq = mb & 2047;
#pragma unroll
        for (int j = 0; j < 4; ++j) {
          const int n = n0 + wn * 64 + j * 16 + l15;
          const int hd = n - 2048;
          us4 o = { f2bf(acc[i][j][0]), f2bf(acc[i][j][1]), f2bf(acc[i][j][2]), f2bf(acc[i][j][3]) };
          *(us4*)(vt_out + (size_t)(b * DMODEL + hd) * SEQ + lseq) = o;
        }
      }
    }
  } else {
#pragma unroll
    for (int i = 0; i < 4; ++i) {
      const int mb = m0 + wm * 64 + i * 16 + g * 4;
#pragma unroll
      for (int j = 0; j < 4; ++j) {
        const int n = n0 + wn * 64 + j * 16 + l15;
#pragma unroll
        for (int r = 0; r < 4; ++r) f_out[(size_t)(mb + r) * DMODEL + n] = acc[i][j][r];
      }
    }
  }
}

// ---------------- causal flash attention v11 ----------------
// DUAL 16-row Q-subtiles per wave (32 q-rows): each LDS K/V fragment read
// feeds BOTH subtiles' MFMAs -> per unit work this halves LDS-read
// instructions, staging writes, barriers, and addressing VALU (the per-CU
// shared-throughput wall identified by v9-vs-v10 flat time at 2x occupancy).
// Block = 4 waves = 128-row q-tile; pairing (15-j, j) -> uniform 34
// iterations; grid 256 blocks (1/CU) with XCD-affinity remap. KVBLK=64
// double-buffered, zero-shuffle K=16 PV, exp2-domain softmax, defer-max,
// m init -1e20 / mask -1e30 (all-masked iteration contributes exactly 0).
__global__ __launch_bounds__(256) void attn_kernel(
    const unsigned short* __restrict__ Qb, const unsigned short* __restrict__ Kb,
    const unsigned short* __restrict__ Vt, unsigned short* __restrict__ Ob) {
  __shared__ __align__(16) unsigned short kv[2][2][4096];  // [buf][K/V][64*64]
  __shared__ __align__(16) unsigned short Olds[4][16][72];
  const int tid = threadIdx.x;
  const int l = tid & 63, w = tid >> 6;
  const int g = l >> 4, q15 = l & 15;

  // XCD-affinity remap (bijective): blocks of one bh share lid mod 8
  const int lid = blockIdx.x + 8 * blockIdx.y;    // 0..255
  const int xcd = lid & 7;
  const int slot = lid >> 3;                      // 0..31
  const int bh = xcd * 4 + (slot & 3);            // 0..31
  const int j = slot >> 2;                        // 0..7

  const int b = bh >> 4, h = bh & 15;
  const int tA = 15 - j;            // long phase q-tile (128 rows)
  const int tB = j;                 // short phase q-tile
  const int lenA = 2 * (tA + 1);    // 64-k tiles in phase A
  const int lenB = 2 * (tB + 1);
  const int nkt = lenA + lenB;      // == 34

  // Q fragments: 2 phases x 2 subtiles x 2 halves
  bf16x8 qf[2][2][2];
  int qsel[2][2];
#pragma unroll
  for (int p = 0; p < 2; ++p) {
    const int t = p ? tB : tA;
#pragma unroll
    for (int s = 0; s < 2; ++s) {
      const int row = t * 128 + w * 32 + s * 16 + q15;
      const unsigned short* qp = Qb + (size_t)(b * SEQ + row) * DMODEL + h * DKH + g * 8;
      qf[p][s][0] = *(const bf16x8*)qp;
      qf[p][s][1] = *(const bf16x8*)(qp + 32);
      qsel[p][s] = row;
    }
  }

  // staging source (pre-swizzled): linear LDS slot o = tid*16 (+4096) holds
  // tile element (row = o>>7, colbyte = (o&127) ^ ((row&7)<<4))
  const int rS = tid >> 3;                                        // rows 0..31 (+32)
  const int cS = (((tid & 7) * 16) ^ ((rS & 7) << 4)) >> 1;       // element col
  const unsigned short* pKg = Kb + (size_t)(b * SEQ + rS) * DMODEL + h * DKH + cS;
  const unsigned short* pVg = Vt + (size_t)(b * DMODEL + h * DKH + rS) * SEQ + cS;

  // swizzled ds_read offsets (elements), reading row has row&7 == q15&7
  const int srow = (q15 & 7) << 4;
  const int oc0 = (srow ^ (g * 16)) >> 1;          // K frag: d-slice g*8..g*8+7
  const int oc1 = (srow ^ (g * 16 + 64)) >> 1;
  // V frag (K=16 A-operand): per blk, 8 bytes at col blk*32 + 8g
  int vc[4];
#pragma unroll
  for (int blk = 0; blk < 4; ++blk) vc[blk] = ((blk * 32 + 8 * g) ^ srow) >> 1;

  const f32x4 zf = {0.f, 0.f, 0.f, 0.f};
  float mr[2] = {-1e20f, -1e20f}, lr[2] = {0.f, 0.f};  // per-subtile; lr per-lane
  f32x4 ot[2][4];
#pragma unroll
  for (int s = 0; s < 2; ++s)
#pragma unroll
    for (int d = 0; d < 4; ++d) ot[s][d] = zf;

  auto STAGE = [&](int bb, int k0) {
    unsigned short* lk = &kv[bb][0][0] + w * 512;  // wave-uniform base
    unsigned short* lv = &kv[bb][1][0] + w * 512;
    gld_lds16(pKg + (size_t)k0 * DMODEL, lk);
    gld_lds16(pKg + (size_t)(k0 + 32) * DMODEL, lk + 2048);
    gld_lds16(pVg + k0, lv);
    gld_lds16(pVg + (size_t)32 * SEQ + k0, lv + 2048);
  };

  auto STORE = [&](int qt) {
#pragma unroll
    for (int s = 0; s < 2; ++s) {
      float ls = lr[s];
      ls += __shfl_xor(ls, 16);
      ls += __shfl_xor(ls, 32);
      const float inv = 1.0f / ls;
#pragma unroll
      for (int d = 0; d < 4; ++d) {
        us4 o = { f2bf(ot[s][d][0] * inv), f2bf(ot[s][d][1] * inv),
                  f2bf(ot[s][d][2] * inv), f2bf(ot[s][d][3] * inv) };
        *(us4*)&Olds[w][q15][d * 16 + g * 4] = o;
      }
      __syncthreads();
      const int r = l >> 2;
      const int c = (l & 3) * 16;
      const us8 v0 = *(const us8*)&Olds[w][r][c];
      const us8 v1 = *(const us8*)&Olds[w][r][c + 8];
      unsigned short* ob = Ob + (size_t)(b * SEQ + qt * 128 + w * 32 + s * 16 + r) * DMODEL + h * DKH + c;
      *(us8*)ob = v0;
      *(us8*)(ob + 8) = v1;
      __syncthreads();
    }
  };

  auto KN = [&](int m) { return (m < lenA) ? m : (m - lenA); };

  STAGE(0, 0);
  __syncthreads();

  for (int i = 0; i < nkt; ++i) {
    const int cur = i & 1;
    const bool phA = (i < lenA);
    const int p = phA ? 0 : 1;
    const int kt = phA ? i : (i - lenA);
    if (i + 1 < nkt) STAGE(cur ^ 1, KN(i + 1) * 64);

    const int t = phA ? tA : tB;
    const bool domask = (kt >= 2 * t);
    const int kb0 = kt * 64;
    const unsigned short* lkb = &kv[cur][0][0] + q15 * 64;
    const unsigned short* lvb = &kv[cur][1][0] + q15 * 64;

    // QK^T both subtiles; K fragments shared
    float sp[2][4][4];
    float mt[2] = {-1e30f, -1e30f};
#pragma unroll
    for (int blk = 0; blk < 4; ++blk) {
      const bf16x8 kf0 = *(const bf16x8*)(lkb + blk * 1024 + oc0);
      const bf16x8 kf1 = *(const bf16x8*)(lkb + blk * 1024 + oc1);
      f32x4 c0 = zf, c1 = zf;
      c0 = __builtin_amdgcn_mfma_f32_16x16x32_bf16(kf0, qf[p][0][0], c0, 0, 0, 0);
      c1 = __builtin_amdgcn_mfma_f32_16x16x32_bf16(kf0, qf[p][1][0], c1, 0, 0, 0);
      c0 = __builtin_amdgcn_mfma_f32_16x16x32_bf16(kf1, qf[p][0][1], c0, 0, 0, 0);
      c1 = __builtin_amdgcn_mfma_f32_16x16x32_bf16(kf1, qf[p][1][1], c1, 0, 0, 0);
#pragma unroll
      for (int r = 0; r < 4; ++r) {
        float s0 = c0[r], s1 = c1[r];
        if (domask) {
          const int kk = kb0 + blk * 16 + g * 4 + r;
          if (kk > qsel[p][0]) s0 = -1e30f;
          if (kk > qsel[p][1]) s1 = -1e30f;
        }
        sp[0][blk][r] = s0; mt[0] = fmaxf(mt[0], s0);
        sp[1][blk][r] = s1; mt[1] = fmaxf(mt[1], s1);
      }
    }
#pragma unroll
    for (int s = 0; s < 2; ++s) {
      mt[s] = fmaxf(mt[s], __shfl_xor(mt[s], 16));
      mt[s] = fmaxf(mt[s], __shfl_xor(mt[s], 32));
      const bool defer = __all(mt[s] - mr[s] <= 8.0f);
      float mnew, alpha;
      if (defer) { mnew = mr[s]; alpha = 1.0f; }
      else { mnew = fmaxf(mr[s], mt[s]); alpha = exp2f(mr[s] - mnew); }
      float rs = 0.f;
#pragma unroll
      for (int blk = 0; blk < 4; ++blk)
#pragma unroll
        for (int r = 0; r < 4; ++r) {
          const float pe = exp2f(sp[s][blk][r] - mnew);
          sp[s][blk][r] = pe;
          rs += pe;
        }
      if (defer) {
        lr[s] += rs;
      } else {
        lr[s] = lr[s] * alpha + rs;
        mr[s] = mnew;
#pragma unroll
        for (int d = 0; d < 4; ++d) ot[s][d] *= alpha;
      }
    }

    // P -> bf16 K=16 B-fragments in-lane (no shuffles)
    short4v pfb[2][4];
#pragma unroll
    for (int s = 0; s < 2; ++s)
#pragma unroll
      for (int blk = 0; blk < 4; ++blk) {
        union { __bf16 hh[4]; short4v v; } pk;
        pk.hh[0] = (__bf16)sp[s][blk][0];
        pk.hh[1] = (__bf16)sp[s][blk][1];
        pk.hh[2] = (__bf16)sp[s][blk][2];
        pk.hh[3] = (__bf16)sp[s][blk][3];
        pfb[s][blk] = pk.v;
      }

    // O^T[s][dt] += sum_blk Vt[16dt+q15][k(blk)] * P_s[k][q]; V frags shared
    __builtin_amdgcn_s_setprio(1);
#pragma unroll
    for (int dt = 0; dt < 4; ++dt) {
      const unsigned short* vrow = lvb + dt * 1024;
      f32x4 o0 = ot[0][dt], o1 = ot[1][dt];
#pragma unroll
      for (int blk = 0; blk < 4; ++blk) {
        const short4v vf = *(const short4v*)(vrow + vc[blk]);
        o0 = __builtin_amdgcn_mfma_f32_16x16x16bf16_1k(vf, pfb[0][blk], o0, 0, 0, 0);
        o1 = __builtin_amdgcn_mfma_f32_16x16x16bf16_1k(vf, pfb[1][blk], o1, 0, 0, 0);
      }
      ot[0][dt] = o0; ot[1][dt] = o1;
    }
    __builtin_amdgcn_s_setprio(0);

    if (phA && kt == lenA - 1) {  // phase switch: flush A, reset state
      STORE(tA);
#pragma unroll
      for (int s = 0; s < 2; ++s) {
        mr[s] = -1e20f; lr[s] = 0.f;
#pragma unroll
        for (int d = 0; d < 4; ++d) ot[s][d] = zf;
      }
    }
    __syncthreads();
  }
  STORE(tB);
}

// ---------------- launch ----------------
extern "C" void kernel_launch(void* const* d_in, const int* in_sizes, int n_in,
                              void* d_out, int out_size, void* d_ws, size_t ws_size,
                              hipStream_t stream) {
  const float* X = (const float*)d_in[0];
  const int* pos = (const int*)d_in[1];
  const float* Wqkv = (const float*)d_in[2];
  const float* Wout = (const float*)d_in[3];
  char* ws = (char*)d_ws;
  unsigned short* xbf    = (unsigned short*)(ws + OFF_XBF);
  unsigned short* wqkvbf = (unsigned short*)(ws + OFF_WQKV);
  unsigned short* woutbf = (unsigned short*)(ws + OFF_WOUT);
  unsigned short* qb     = (unsigned short*)(ws + OFF_Q);
  unsigned short* kbuf   = (unsigned short*)(ws + OFF_K);
  unsigned short* vt     = (unsigned short*)(ws + OFF_VT);
  unsigned short* ob     = (unsigned short*)(ws + OFF_O);
  float2* rope           = (float2*)(ws + OFF_ROPE);

  prep_kernel<<<8192, 256, 0, stream>>>(X, Wqkv, Wout, pos, xbf, wqkvbf, woutbf, rope);
  gemm_kernel<0><<<dim3(NQKV / 128, MTOT / 128), 256, 0, stream>>>(
      xbf, wqkvbf, qb, kbuf, vt, rope, nullptr);
  attn_kernel<<<dim3(8, 32), 256, 0, stream>>>(qb, kbuf, vt, ob);
  gemm_kernel<1><<<dim3(DMODEL / 128, MTOT / 128), 256, 0, stream>>>(
      ob, woutbf, nullptr, nullptr, nullptr, nullptr, (float*)d_out);
}

// Round 12
// 136.848 us; speedup vs baseline: 1.2757x; 1.2757x over previous
//
#include <hip/hip_runtime.h>
#include <stdint.h>
#include <stddef.h>
#include <math.h>

#define DEVINL __device__ __forceinline__

typedef __attribute__((ext_vector_type(8))) __bf16 bf16x8;
typedef __attribute__((ext_vector_type(4))) float f32x4;
typedef __attribute__((ext_vector_type(4))) unsigned short us4;
typedef __attribute__((ext_vector_type(8))) unsigned short us8;
typedef __attribute__((ext_vector_type(4))) short short4v;  // K=16 MFMA A/B operand

typedef __attribute__((address_space(1))) unsigned int as1_uint;
typedef __attribute__((address_space(3))) unsigned int as3_uint;

constexpr int SEQ    = 2048;
constexpr int DMODEL = 1024;
constexpr int MTOT   = 4096;    // B*L
constexpr int NQKV   = 3072;
constexpr int DKH    = 64;

// workspace layout (bytes)
constexpr size_t OFF_XBF  = 0;                                      // 8 MiB
constexpr size_t OFF_WQKV = OFF_XBF  + (size_t)MTOT * DMODEL * 2;   // 6 MiB
constexpr size_t OFF_WOUT = OFF_WQKV + (size_t)NQKV * DMODEL * 2;   // 2 MiB
constexpr size_t OFF_Q    = OFF_WOUT + (size_t)DMODEL * DMODEL * 2; // 8 MiB
constexpr size_t OFF_K    = OFF_Q    + (size_t)MTOT * DMODEL * 2;   // 8 MiB
constexpr size_t OFF_VT   = OFF_K    + (size_t)MTOT * DMODEL * 2;   // 8 MiB
constexpr size_t OFF_O    = OFF_VT   + (size_t)MTOT * DMODEL * 2;   // 8 MiB
constexpr size_t OFF_ROPE = OFF_O    + (size_t)MTOT * DMODEL * 2;   // 1 MiB

// Q pre-scale: 1/sqrt(64) * log2(e) -> softmax runs in exp2 domain
constexpr float QSCALE = 0.125f * 1.4426950408889634f;

DEVINL unsigned short f2bf(float f) {
  unsigned int u = __float_as_uint(f);
  u += 0x7fffu + ((u >> 16) & 1u);
  return (unsigned short)(u >> 16);
}

DEVINL float fexp2(float x) { return __builtin_amdgcn_exp2f(x); }  // 1x v_exp_f32

DEVINL void gld_lds16(const unsigned short* g, unsigned short* s) {
  __builtin_amdgcn_global_load_lds((as1_uint*)g, (as3_uint*)s, 16, 0, 0);
}

// ---------------- prep: fp32->bf16 converts + rope table ----------------
__global__ __launch_bounds__(256) void prep_kernel(
    const float* __restrict__ X, const float* __restrict__ Wqkv,
    const float* __restrict__ Wout, const int* __restrict__ pos,
    unsigned short* __restrict__ xbf, unsigned short* __restrict__ wqkvbf,
    unsigned short* __restrict__ woutbf, float2* __restrict__ rope) {
  const int t = blockIdx.x * 256 + threadIdx.x;
  if (t < MTOT * 32) {  // rope table: (m, pair)
    const int m = t >> 5, ip = t & 31;
    const float freq = powf(10000.0f, -(float)(2 * ip) / 64.0f);
    const float ang = (float)pos[m] * freq;
    float sv, cv;
    sincosf(ang, &sv, &cv);
    rope[t] = make_float2(cv, sv);
  }
  const int NX = MTOT * DMODEL, NW1 = NQKV * DMODEL, NW2 = DMODEL * DMODEL;
  const int e = t * 4;
  const float* src;
  unsigned short* dst;
  if (e < NX) { src = X + e; dst = xbf + e; }
  else if (e < NX + NW1) { src = Wqkv + (e - NX); dst = wqkvbf + (e - NX); }
  else if (e < NX + NW1 + NW2) { src = Wout + (e - NX - NW1); dst = woutbf + (e - NX - NW1); }
  else return;
  const float4 v = *(const float4*)src;
  us4 o = { f2bf(v.x), f2bf(v.y), f2bf(v.z), f2bf(v.w) };
  *(us4*)dst = o;
}

// ---------------- GEMM: C[m][n] = sum_k A[m][k]*B[n][k], 128x128 tile ----------------
// MODE 0: A=Xbf, B=Wqkv -> RoPE epilogue, scatter Q (pre-scaled) / K row-major,
//         V transposed per head.
// MODE 1: A=Obf,  B=Wout -> fp32 store to d_out.
template <int MODE>
__global__ __launch_bounds__(256) void gemm_kernel(
    const unsigned short* __restrict__ A, const unsigned short* __restrict__ Bw,
    unsigned short* __restrict__ q_out, unsigned short* __restrict__ k_out,
    unsigned short* __restrict__ vt_out, const float2* __restrict__ rope,
    float* __restrict__ f_out) {
  constexpr int K = DMODEL;  // 1024
  __shared__ __align__(16) unsigned short As[128 * 32];
  __shared__ __align__(16) unsigned short Bs[128 * 32];
  const int tid = threadIdx.x;
  const int l = tid & 63, w = tid >> 6;
  const int g = l >> 4, l15 = l & 15;
  const int m0 = blockIdx.y * 128, n0 = blockIdx.x * 128;
  const int wm = w >> 1, wn = w & 1;

  // staging: per wave 1KiB per instr; lane chunk = base + l*16 bytes in LDS
  const unsigned short* ag = A  + (size_t)(m0 + w * 16 + (l >> 2)) * K + (l & 3) * 8;
  const unsigned short* bg = Bw + (size_t)(n0 + w * 16 + (l >> 2)) * K + (l & 3) * 8;
  unsigned short* as0 = As + w * 512;
  unsigned short* bs0 = Bs + w * 512;

  const f32x4 zf = {0.f, 0.f, 0.f, 0.f};
  f32x4 acc[4][4];
#pragma unroll
  for (int i = 0; i < 4; ++i)
#pragma unroll
    for (int j = 0; j < 4; ++j) acc[i][j] = zf;

  for (int kt = 0; kt < K / 32; ++kt) {
    const unsigned short* a0 = ag + kt * 32;
    const unsigned short* b0 = bg + kt * 32;
    gld_lds16(a0, as0);
    gld_lds16(a0 + (size_t)64 * K, as0 + 2048);
    gld_lds16(b0, bs0);
    gld_lds16(b0 + (size_t)64 * K, bs0 + 2048);
    __syncthreads();
    bf16x8 af[4], bf[4];
#pragma unroll
    for (int i = 0; i < 4; ++i)
      af[i] = *(const bf16x8*)(As + (wm * 64 + i * 16 + l15) * 32 + g * 8);
#pragma unroll
    for (int j = 0; j < 4; ++j)
      bf[j] = *(const bf16x8*)(Bs + (wn * 64 + j * 16 + l15) * 32 + g * 8);
#pragma unroll
    for (int i = 0; i < 4; ++i)
#pragma unroll
      for (int j = 0; j < 4; ++j)
        acc[i][j] = __builtin_amdgcn_mfma_f32_16x16x32_bf16(af[i], bf[j], acc[i][j], 0, 0, 0);
    __syncthreads();
  }

  if constexpr (MODE == 0) {
    const int region = n0 >> 10;  // 0=Q 1=K 2=V (128 | 1024 region boundaries)
    if (region <= 1) {
      unsigned short* outb = (region == 0) ? q_out : k_out;
      const float qs = (region == 0) ? QSCALE : 1.0f;
#pragma unroll
      for (int i = 0; i < 4; ++i) {
        const int mb = m0 + wm * 64 + i * 16 + g * 4;
#pragma unroll
        for (int j = 0; j < 4; ++j) {
          const int n = n0 + wn * 64 + j * 16 + l15;
          const int ncol = n & 1023;
          const int ip = (n & 63) >> 1;
          const float sgn = (n & 1) ? 1.f : -1.f;
#pragma unroll
          for (int r = 0; r < 4; ++r) {
            const int m = mb + r;
            const float v = acc[i][j][r];
            const float p = __shfl_xor(v, 1);  // partner column n^1
            const float2 cs = rope[m * 32 + ip];
            const float o = (v * cs.x + sgn * p * cs.y) * qs;
            outb[(size_t)m * DMODEL + ncol] = f2bf(o);
          }
        }
      }
    } else {  // V -> transposed per head: Vt[(b*1024 + h*64 + d)][l]
#pragma unroll
      for (int i = 0; i < 4; ++i) {
        const int mb = m0 + wm * 64 + i * 16 + g * 4;
        const int b = mb >> 11;
        const int lseq = mb & 2047;
#pragma unroll
        for (int j = 0; j < 4; ++j) {
          const int n = n0 + wn * 64 + j * 16 + l15;
          const int hd = n - 2048;
          us4 o = { f2bf(acc[i][j][0]), f2bf(acc[i][j][1]), f2bf(acc[i][j][2]), f2bf(acc[i][j][3]) };
          *(us4*)(vt_out + (size_t)(b * DMODEL + hd) * SEQ + lseq) = o;
        }
      }
    }
  } else {
#pragma unroll
    for (int i = 0; i < 4; ++i) {
      const int mb = m0 + wm * 64 + i * 16 + g * 4;
#pragma unroll
      for (int j = 0; j < 4; ++j) {
        const int n = n0 + wn * 64 + j * 16 + l15;
#pragma unroll
        for (int r = 0; r < 4; ++r) f_out[(size_t)(mb + r) * DMODEL + n] = acc[i][j][r];
      }
    }
  }
}

// ---------------- causal flash attention v12 ----------------
// v9 structure (pairing (31-j, j), 4 waves x 16 q-rows, XCD-affinity remap,
// KVBLK=64 double-buffered, zero-shuffle K=16 PV) with PEELED control flow:
// phase-A main loop (NO mask code), phase-A diagonal (mask), phase-B main,
// phase-B diagonal. domask passed as a literal to an inlined lambda ->
// constant-folded; Q fragments hoisted to call sites (no per-iter selects).
// exp2 via __builtin_amdgcn_exp2f (guaranteed 1x v_exp_f32).
__global__ __launch_bounds__(256) void attn_kernel(
    const unsigned short* __restrict__ Qb, const unsigned short* __restrict__ Kb,
    const unsigned short* __restrict__ Vt, unsigned short* __restrict__ Ob) {
  __shared__ __align__(16) unsigned short kv[2][2][4096];  // [buf][K/V][64*64]
  __shared__ __align__(16) unsigned short Olds[4][16][72];
  const int tid = threadIdx.x;
  const int l = tid & 63, w = tid >> 6;
  const int g = l >> 4, q15 = l & 15;

  // XCD-affinity remap (bijective): blocks of one bh share lid mod 8
  const int lid = blockIdx.x + 16 * blockIdx.y;   // 0..511
  const int xcd = lid & 7;
  const int slot = lid >> 3;                      // 0..63
  const int bh = xcd * 4 + (slot & 3);            // 0..31
  const int j = slot >> 2;                        // 0..15

  const int b = bh >> 4, h = bh & 15;
  const int tA = 31 - j;            // long phase q-tile
  const int tB = j;                 // short phase q-tile

  // Q fragments for both phases (16 q-rows per wave)
  const unsigned short* qpA = Qb + (size_t)(b * SEQ + tA * 64 + w * 16 + q15) * DMODEL + h * DKH + g * 8;
  const unsigned short* qpB = Qb + (size_t)(b * SEQ + tB * 64 + w * 16 + q15) * DMODEL + h * DKH + g * 8;
  const bf16x8 qA0 = *(const bf16x8*)qpA, qA1 = *(const bf16x8*)(qpA + 32);
  const bf16x8 qB0 = *(const bf16x8*)qpB, qB1 = *(const bf16x8*)(qpB + 32);
  const int qselA = tA * 64 + w * 16 + q15;
  const int qselB = tB * 64 + w * 16 + q15;

  // staging source (pre-swizzled): linear LDS slot o = tid*16 (+4096) holds
  // tile element (row = o>>7, colbyte = (o&127) ^ ((row&7)<<4))
  const int rS = tid >> 3;                                        // rows 0..31 (+32)
  const int cS = (((tid & 7) * 16) ^ ((rS & 7) << 4)) >> 1;       // element col
  const unsigned short* pKg = Kb + (size_t)(b * SEQ + rS) * DMODEL + h * DKH + cS;
  const unsigned short* pVg = Vt + (size_t)(b * DMODEL + h * DKH + rS) * SEQ + cS;

  // swizzled ds_read offsets (elements), reading row has row&7 == q15&7
  const int srow = (q15 & 7) << 4;
  const int oc0 = (srow ^ (g * 16)) >> 1;          // K frag: d-slice g*8..g*8+7
  const int oc1 = (srow ^ (g * 16 + 64)) >> 1;
  // V frag (K=16 A-operand): per blk, 8 bytes at col blk*32 + 8g
  int vc[4];
#pragma unroll
  for (int blk = 0; blk < 4; ++blk) vc[blk] = ((blk * 32 + 8 * g) ^ srow) >> 1;

  const f32x4 zf = {0.f, 0.f, 0.f, 0.f};
  float mrun = -1e30f, lrun = 0.f;   // lrun = per-lane partial row sum
  f32x4 ot[4];
#pragma unroll
  for (int d = 0; d < 4; ++d) ot[d] = zf;

  auto STAGE = [&](int bb, int k0) {
    unsigned short* lk = &kv[bb][0][0] + w * 512;  // wave-uniform base
    unsigned short* lv = &kv[bb][1][0] + w * 512;
    gld_lds16(pKg + (size_t)k0 * DMODEL, lk);
    gld_lds16(pKg + (size_t)(k0 + 32) * DMODEL, lk + 2048);
    gld_lds16(pVg + k0, lv);
    gld_lds16(pVg + (size_t)32 * SEQ + k0, lv + 2048);
  };

  auto STORE = [&](int qt) {
    float lr = lrun;
    lr += __shfl_xor(lr, 16);
    lr += __shfl_xor(lr, 32);
    const float inv = 1.0f / lr;
#pragma unroll
    for (int d = 0; d < 4; ++d) {
      us4 o = { f2bf(ot[d][0] * inv), f2bf(ot[d][1] * inv), f2bf(ot[d][2] * inv), f2bf(ot[d][3] * inv) };
      *(us4*)&Olds[w][q15][d * 16 + g * 4] = o;
    }
    __syncthreads();
    const int r = l >> 2;
    const int c = (l & 3) * 16;
    const us8 v0 = *(const us8*)&Olds[w][r][c];
    const us8 v1 = *(const us8*)&Olds[w][r][c + 8];
    unsigned short* ob = Ob + (size_t)(b * SEQ + qt * 64 + w * 16 + r) * DMODEL + h * DKH + c;
    *(us8*)ob = v0;
    *(us8*)(ob + 8) = v1;
  };

  // one k-tile: QK^T -> online softmax -> in-lane P pack -> K=16 PV.
  // domask is ALWAYS a literal at call sites -> constant-folded.
  auto ITER = [&](int cur, int kb0, bf16x8 qf0, bf16x8 qf1, int qsel, bool domask) {
    const unsigned short* lkb = &kv[cur][0][0] + q15 * 64;
    const unsigned short* lvb = &kv[cur][1][0] + q15 * 64;

    float sp[4][4];
    float mt = -1e30f;
#pragma unroll
    for (int blk = 0; blk < 4; ++blk) {
      const bf16x8 kf0 = *(const bf16x8*)(lkb + blk * 1024 + oc0);
      const bf16x8 kf1 = *(const bf16x8*)(lkb + blk * 1024 + oc1);
      f32x4 c = zf;
      c = __builtin_amdgcn_mfma_f32_16x16x32_bf16(kf0, qf0, c, 0, 0, 0);
      c = __builtin_amdgcn_mfma_f32_16x16x32_bf16(kf1, qf1, c, 0, 0, 0);
#pragma unroll
      for (int r = 0; r < 4; ++r) {
        float s = c[r];  // already in exp2 domain (Q pre-scaled)
        if (domask && (kb0 + blk * 16 + g * 4 + r > qsel)) s = -1e30f;
        sp[blk][r] = s;
        mt = fmaxf(mt, s);
      }
    }
    mt = fmaxf(mt, __shfl_xor(mt, 16));
    mt = fmaxf(mt, __shfl_xor(mt, 32));

    const bool defer = __all(mt - mrun <= 8.0f);
    float mnew, alpha;
    if (defer) { mnew = mrun; alpha = 1.0f; }
    else { mnew = fmaxf(mrun, mt); alpha = fexp2(mrun - mnew); }

    float rs = 0.f;
#pragma unroll
    for (int blk = 0; blk < 4; ++blk)
#pragma unroll
      for (int r = 0; r < 4; ++r) {
        const float p = fexp2(sp[blk][r] - mnew);
        sp[blk][r] = p;
        rs += p;
      }
    if (defer) {
      lrun += rs;                 // per-lane partial; cross-lane reduce at STORE
    } else {
      lrun = lrun * alpha + rs;
      mrun = mnew;
#pragma unroll
      for (int d = 0; d < 4; ++d) ot[d] *= alpha;
    }

    // P -> bf16 K=16 B-fragments in-lane (no shuffles): pfb[blk] holds
    // P[k=kb0+blk*16+4g+i][q15], i=0..3 — exactly the 16x16x16 B layout.
    short4v pfb[4];
#pragma unroll
    for (int blk = 0; blk < 4; ++blk) {
      union { __bf16 hh[4]; short4v v; } pk;
      pk.hh[0] = (__bf16)sp[blk][0];
      pk.hh[1] = (__bf16)sp[blk][1];
      pk.hh[2] = (__bf16)sp[blk][2];
      pk.hh[3] = (__bf16)sp[blk][3];
      pfb[blk] = pk.v;
    }

    // O^T[dt][q] += sum_blk Vt[16dt+q15][k(blk)] * P[k(blk)][q]  (K=16 MFMAs)
    __builtin_amdgcn_s_setprio(1);
#pragma unroll
    for (int dt = 0; dt < 4; ++dt) {
      const unsigned short* vrow = lvb + dt * 1024;
      f32x4 o = ot[dt];
#pragma unroll
      for (int blk = 0; blk < 4; ++blk) {
        const short4v vf = *(const short4v*)(vrow + vc[blk]);
        o = __builtin_amdgcn_mfma_f32_16x16x16bf16_1k(vf, pfb[blk], o, 0, 0, 0);
      }
      ot[dt] = o;
    }
    __builtin_amdgcn_s_setprio(0);
  };

  STAGE(0, 0);
  __syncthreads();
  int cur = 0;

  // ---- phase A main (no mask) ----
  for (int i = 0; i < tA; ++i) {
    STAGE(cur ^ 1, (i + 1) * 64);
    ITER(cur, i * 64, qA0, qA1, qselA, false);
    __syncthreads();
    cur ^= 1;
  }
  // ---- phase A diagonal (mask) + prefetch phase-B tile 0 ----
  STAGE(cur ^ 1, 0);
  ITER(cur, tA * 64, qA0, qA1, qselA, true);
  STORE(tA);
  mrun = -1e30f; lrun = 0.f;
#pragma unroll
  for (int d = 0; d < 4; ++d) ot[d] = zf;
  __syncthreads();
  cur ^= 1;

  // ---- phase B main (no mask) ----
  for (int i = 0; i < tB; ++i) {
    STAGE(cur ^ 1, (i + 1) * 64);
    ITER(cur, i * 64, qB0, qB1, qselB, false);
    __syncthreads();
    cur ^= 1;
  }
  // ---- phase B diagonal (mask) ----
  ITER(cur, tB * 64, qB0, qB1, qselB, true);
  STORE(tB);
}

// ---------------- launch ----------------
extern "C" void kernel_launch(void* const* d_in, const int* in_sizes, int n_in,
                              void* d_out, int out_size, void* d_ws, size_t ws_size,
                              hipStream_t stream) {
  const float* X = (const float*)d_in[0];
  const int* pos = (const int*)d_in[1];
  const float* Wqkv = (const float*)d_in[2];
  const float* Wout = (const float*)d_in[3];
  char* ws = (char*)d_ws;
  unsigned short* xbf    = (unsigned short*)(ws + OFF_XBF);
  unsigned short* wqkvbf = (unsigned short*)(ws + OFF_WQKV);
  unsigned short* woutbf = (unsigned short*)(ws + OFF_WOUT);
  unsigned short* qb     = (unsigned short*)(ws + OFF_Q);
  unsigned short* kbuf   = (unsigned short*)(ws + OFF_K);
  unsigned short* vt     = (unsigned short*)(ws + OFF_VT);
  unsigned short* ob     = (unsigned short*)(ws + OFF_O);
  float2* rope           = (float2*)(ws + OFF_ROPE);

  prep_kernel<<<8192, 256, 0, stream>>>(X, Wqkv, Wout, pos, xbf, wqkvbf, woutbf, rope);
  gemm_kernel<0><<<dim3(NQKV / 128, MTOT / 128), 256, 0, stream>>>(
      xbf, wqkvbf, qb, kbuf, vt, rope, nullptr);
  attn_kernel<<<dim3(16, 32), 256, 0, stream>>>(qb, kbuf, vt, ob);
  gemm_kernel<1><<<dim3(DMODEL / 128, MTOT / 128), 256, 0, stream>>>(
      ob, woutbf, nullptr, nullptr, nullptr, nullptr, (float*)d_out);
}

// Round 13
// 123.706 us; speedup vs baseline: 1.4112x; 1.1062x over previous
//
#include <hip/hip_runtime.h>
#include <stdint.h>
#include <stddef.h>
#include <math.h>

#define DEVINL __device__ __forceinline__

typedef __attribute__((ext_vector_type(8))) __bf16 bf16x8;
typedef __attribute__((ext_vector_type(4))) float f32x4;
typedef __attribute__((ext_vector_type(4))) unsigned short us4;
typedef __attribute__((ext_vector_type(8))) unsigned short us8;
typedef __attribute__((ext_vector_type(4))) short short4v;  // K=16 MFMA A/B operand

typedef __attribute__((address_space(1))) unsigned int as1_uint;
typedef __attribute__((address_space(3))) unsigned int as3_uint;

constexpr int SEQ    = 2048;
constexpr int DMODEL = 1024;
constexpr int MTOT   = 4096;    // B*L
constexpr int NQKV   = 3072;
constexpr int DKH    = 64;

// workspace layout (bytes)
constexpr size_t OFF_XBF  = 0;                                      // 8 MiB
constexpr size_t OFF_WQKV = OFF_XBF  + (size_t)MTOT * DMODEL * 2;   // 6 MiB
constexpr size_t OFF_WOUT = OFF_WQKV + (size_t)NQKV * DMODEL * 2;   // 2 MiB
constexpr size_t OFF_Q    = OFF_WOUT + (size_t)DMODEL * DMODEL * 2; // 8 MiB
constexpr size_t OFF_K    = OFF_Q    + (size_t)MTOT * DMODEL * 2;   // 8 MiB
constexpr size_t OFF_VT   = OFF_K    + (size_t)MTOT * DMODEL * 2;   // 8 MiB
constexpr size_t OFF_O    = OFF_VT   + (size_t)MTOT * DMODEL * 2;   // 8 MiB
constexpr size_t OFF_ROPE = OFF_O    + (size_t)MTOT * DMODEL * 2;   // 1 MiB

// Q pre-scale: 1/sqrt(64) * log2(e) -> softmax runs in exp2 domain
constexpr float QSCALE = 0.125f * 1.4426950408889634f;

DEVINL unsigned short f2bf(float f) {
  unsigned int u = __float_as_uint(f);
  u += 0x7fffu + ((u >> 16) & 1u);
  return (unsigned short)(u >> 16);
}

DEVINL float fexp2(float x) { return __builtin_amdgcn_exp2f(x); }  // 1x v_exp_f32

DEVINL void gld_lds16(const unsigned short* g, unsigned short* s) {
  __builtin_amdgcn_global_load_lds((as1_uint*)g, (as3_uint*)s, 16, 0, 0);
}

// ---------------- prep: fp32->bf16 converts + rope table ----------------
__global__ __launch_bounds__(256) void prep_kernel(
    const float* __restrict__ X, const float* __restrict__ Wqkv,
    const float* __restrict__ Wout, const int* __restrict__ pos,
    unsigned short* __restrict__ xbf, unsigned short* __restrict__ wqkvbf,
    unsigned short* __restrict__ woutbf, float2* __restrict__ rope) {
  const int t = blockIdx.x * 256 + threadIdx.x;
  if (t < MTOT * 32) {  // rope table: (m, pair)
    const int m = t >> 5, ip = t & 31;
    const float freq = powf(10000.0f, -(float)(2 * ip) / 64.0f);
    const float ang = (float)pos[m] * freq;
    float sv, cv;
    sincosf(ang, &sv, &cv);
    rope[t] = make_float2(cv, sv);
  }
  const int NX = MTOT * DMODEL, NW1 = NQKV * DMODEL, NW2 = DMODEL * DMODEL;
  const int e = t * 4;
  const float* src;
  unsigned short* dst;
  if (e < NX) { src = X + e; dst = xbf + e; }
  else if (e < NX + NW1) { src = Wqkv + (e - NX); dst = wqkvbf + (e - NX); }
  else if (e < NX + NW1 + NW2) { src = Wout + (e - NX - NW1); dst = woutbf + (e - NX - NW1); }
  else return;
  const float4 v = *(const float4*)src;
  us4 o = { f2bf(v.x), f2bf(v.y), f2bf(v.z), f2bf(v.w) };
  *(us4*)dst = o;
}

// ---------------- GEMM: C[m][n] = sum_k A[m][k]*B[n][k] ----------------
// 128x128 tile, BK=64 as two 32-col sub-tiles (exact m97 staging/fragment
// geometry x2 -> 8 gld_lds + 16 ds_read + 32 MFMA per iteration, HALF the
// barrier/vmcnt-drain count of BK=32). XCD-chunked block swizzle: each XCD
// owns a contiguous 8m x CHN-n chunk -> per-XCD L2 working set ~5MB (MODE0)
// / 3MB (MODE1) instead of the full 14MB (all 768 blocks are co-resident).
// MODE 0: A=Xbf, B=Wqkv -> RoPE epilogue, Q (pre-scaled) / K row-major,
//         V transposed per head.  MODE 1: A=Obf, B=Wout -> fp32 out.
template <int MODE>
__global__ __launch_bounds__(256) void gemm_kernel(
    const unsigned short* __restrict__ A, const unsigned short* __restrict__ Bw,
    unsigned short* __restrict__ q_out, unsigned short* __restrict__ k_out,
    unsigned short* __restrict__ vt_out, const float2* __restrict__ rope,
    float* __restrict__ f_out) {
  constexpr int K = DMODEL;  // 1024
  __shared__ __align__(16) unsigned short As[2][128 * 32];
  __shared__ __align__(16) unsigned short Bs[2][128 * 32];
  const int tid = threadIdx.x;
  const int l = tid & 63, w = tid >> 6;
  const int g = l >> 4, l15 = l & 15;

  // XCD-chunked swizzle (bijective)
  constexpr int GX  = (MODE == 0) ? 24 : 8;   // gridDim.x (n-blocks)
  constexpr int CHN = (MODE == 0) ? 12 : 4;   // n-blocks per XCD chunk
  const int lid = blockIdx.x + GX * blockIdx.y;
  const int xcd = lid & 7;
  const int sc  = lid >> 3;                   // slot in chunk
  const int bm = (xcd & 3) * 8 + (sc & 7);
  const int bn = (xcd >> 2) * CHN + (sc >> 3);
  const int m0 = bm * 128, n0 = bn * 128;
  const int wm = w >> 1, wn = w & 1;

  // staging: per wave 1KiB per instr; lane chunk = base + l*16 bytes in LDS
  const unsigned short* ag = A  + (size_t)(m0 + w * 16 + (l >> 2)) * K + (l & 3) * 8;
  const unsigned short* bg = Bw + (size_t)(n0 + w * 16 + (l >> 2)) * K + (l & 3) * 8;

  const f32x4 zf = {0.f, 0.f, 0.f, 0.f};
  f32x4 acc[4][4];
#pragma unroll
  for (int i = 0; i < 4; ++i)
#pragma unroll
    for (int j = 0; j < 4; ++j) acc[i][j] = zf;

  for (int kt = 0; kt < K / 64; ++kt) {
#pragma unroll
    for (int kk = 0; kk < 2; ++kk) {
      const unsigned short* a0 = ag + kt * 64 + kk * 32;
      const unsigned short* b0 = bg + kt * 64 + kk * 32;
      unsigned short* as0 = &As[kk][0] + w * 512;
      unsigned short* bs0 = &Bs[kk][0] + w * 512;
      gld_lds16(a0, as0);
      gld_lds16(a0 + (size_t)64 * K, as0 + 2048);
      gld_lds16(b0, bs0);
      gld_lds16(b0 + (size_t)64 * K, bs0 + 2048);
    }
    __syncthreads();
    bf16x8 af[4][2], bf[4][2];
#pragma unroll
    for (int i = 0; i < 4; ++i)
#pragma unroll
      for (int kk = 0; kk < 2; ++kk) {
        af[i][kk] = *(const bf16x8*)(&As[kk][0] + (wm * 64 + i * 16 + l15) * 32 + g * 8);
        bf[i][kk] = *(const bf16x8*)(&Bs[kk][0] + (wn * 64 + i * 16 + l15) * 32 + g * 8);
      }
#pragma unroll
    for (int i = 0; i < 4; ++i)
#pragma unroll
      for (int j = 0; j < 4; ++j) {
        acc[i][j] = __builtin_amdgcn_mfma_f32_16x16x32_bf16(af[i][0], bf[j][0], acc[i][j], 0, 0, 0);
        acc[i][j] = __builtin_amdgcn_mfma_f32_16x16x32_bf16(af[i][1], bf[j][1], acc[i][j], 0, 0, 0);
      }
    __syncthreads();
  }

  if constexpr (MODE == 0) {
    const int region = n0 >> 10;  // 0=Q 1=K 2=V (128 | 1024 region boundaries)
    if (region <= 1) {
      unsigned short* outb = (region == 0) ? q_out : k_out;
      const float qs = (region == 0) ? QSCALE : 1.0f;
#pragma unroll
      for (int i = 0; i < 4; ++i) {
        const int mb = m0 + wm * 64 + i * 16 + g * 4;
#pragma unroll
        for (int j = 0; j < 4; ++j) {
          const int n = n0 + wn * 64 + j * 16 + l15;
          const int ncol = n & 1023;
          const int ip = (n & 63) >> 1;
          const float sgn = (n & 1) ? 1.f : -1.f;
#pragma unroll
          for (int r = 0; r < 4; ++r) {
            const int m = mb + r;
            const float v = acc[i][j][r];
            const float p = __shfl_xor(v, 1);  // partner column n^1
            const float2 cs = rope[m * 32 + ip];
            const float o = (v * cs.x + sgn * p * cs.y) * qs;
            outb[(size_t)m * DMODEL + ncol] = f2bf(o);
          }
        }
      }
    } else {  // V -> transposed per head: Vt[(b*1024 + h*64 + d)][l]
#pragma unroll
      for (int i = 0; i < 4; ++i) {
        const int mb = m0 + wm * 64 + i * 16 + g * 4;
        const int b = mb >> 11;
        const int lseq = mb & 2047;
#pragma unroll
        for (int j = 0; j < 4; ++j) {
          const int n = n0 + wn * 64 + j * 16 + l15;
          const int hd = n - 2048;
          us4 o = { f2bf(acc[i][j][0]), f2bf(acc[i][j][1]), f2bf(acc[i][j][2]), f2bf(acc[i][j][3]) };
          *(us4*)(vt_out + (size_t)(b * DMODEL + hd) * SEQ + lseq) = o;
        }
      }
    }
  } else {
#pragma unroll
    for (int i = 0; i < 4; ++i) {
      const int mb = m0 + wm * 64 + i * 16 + g * 4;
#pragma unroll
      for (int j = 0; j < 4; ++j) {
        const int n = n0 + wn * 64 + j * 16 + l15;
#pragma unroll
        for (int r = 0; r < 4; ++r) f_out[(size_t)(mb + r) * DMODEL + n] = acc[i][j][r];
      }
    }
  }
}

// ---------------- causal flash attention v12 (unchanged from round 12) ----------------
__global__ __launch_bounds__(256) void attn_kernel(
    const unsigned short* __restrict__ Qb, const unsigned short* __restrict__ Kb,
    const unsigned short* __restrict__ Vt, unsigned short* __restrict__ Ob) {
  __shared__ __align__(16) unsigned short kv[2][2][4096];  // [buf][K/V][64*64]
  __shared__ __align__(16) unsigned short Olds[4][16][72];
  const int tid = threadIdx.x;
  const int l = tid & 63, w = tid >> 6;
  const int g = l >> 4, q15 = l & 15;

  // XCD-affinity remap (bijective): blocks of one bh share lid mod 8
  const int lid = blockIdx.x + 16 * blockIdx.y;   // 0..511
  const int xcd = lid & 7;
  const int slot = lid >> 3;                      // 0..63
  const int bh = xcd * 4 + (slot & 3);            // 0..31
  const int j = slot >> 2;                        // 0..15

  const int b = bh >> 4, h = bh & 15;
  const int tA = 31 - j;            // long phase q-tile
  const int tB = j;                 // short phase q-tile

  // Q fragments for both phases (16 q-rows per wave)
  const unsigned short* qpA = Qb + (size_t)(b * SEQ + tA * 64 + w * 16 + q15) * DMODEL + h * DKH + g * 8;
  const unsigned short* qpB = Qb + (size_t)(b * SEQ + tB * 64 + w * 16 + q15) * DMODEL + h * DKH + g * 8;
  const bf16x8 qA0 = *(const bf16x8*)qpA, qA1 = *(const bf16x8*)(qpA + 32);
  const bf16x8 qB0 = *(const bf16x8*)qpB, qB1 = *(const bf16x8*)(qpB + 32);
  const int qselA = tA * 64 + w * 16 + q15;
  const int qselB = tB * 64 + w * 16 + q15;

  // staging source (pre-swizzled): linear LDS slot o = tid*16 (+4096) holds
  // tile element (row = o>>7, colbyte = (o&127) ^ ((row&7)<<4))
  const int rS = tid >> 3;                                        // rows 0..31 (+32)
  const int cS = (((tid & 7) * 16) ^ ((rS & 7) << 4)) >> 1;       // element col
  const unsigned short* pKg = Kb + (size_t)(b * SEQ + rS) * DMODEL + h * DKH + cS;
  const unsigned short* pVg = Vt + (size_t)(b * DMODEL + h * DKH + rS) * SEQ + cS;

  // swizzled ds_read offsets (elements), reading row has row&7 == q15&7
  const int srow = (q15 & 7) << 4;
  const int oc0 = (srow ^ (g * 16)) >> 1;          // K frag: d-slice g*8..g*8+7
  const int oc1 = (srow ^ (g * 16 + 64)) >> 1;
  // V frag (K=16 A-operand): per blk, 8 bytes at col blk*32 + 8g
  int vc[4];
#pragma unroll
  for (int blk = 0; blk < 4; ++blk) vc[blk] = ((blk * 32 + 8 * g) ^ srow) >> 1;

  const f32x4 zf = {0.f, 0.f, 0.f, 0.f};
  float mrun = -1e30f, lrun = 0.f;   // lrun = per-lane partial row sum
  f32x4 ot[4];
#pragma unroll
  for (int d = 0; d < 4; ++d) ot[d] = zf;

  auto STAGE = [&](int bb, int k0) {
    unsigned short* lk = &kv[bb][0][0] + w * 512;  // wave-uniform base
    unsigned short* lv = &kv[bb][1][0] + w * 512;
    gld_lds16(pKg + (size_t)k0 * DMODEL, lk);
    gld_lds16(pKg + (size_t)(k0 + 32) * DMODEL, lk + 2048);
    gld_lds16(pVg + k0, lv);
    gld_lds16(pVg + (size_t)32 * SEQ + k0, lv + 2048);
  };

  auto STORE = [&](int qt) {
    float lr = lrun;
    lr += __shfl_xor(lr, 16);
    lr += __shfl_xor(lr, 32);
    const float inv = 1.0f / lr;
#pragma unroll
    for (int d = 0; d < 4; ++d) {
      us4 o = { f2bf(ot[d][0] * inv), f2bf(ot[d][1] * inv), f2bf(ot[d][2] * inv), f2bf(ot[d][3] * inv) };
      *(us4*)&Olds[w][q15][d * 16 + g * 4] = o;
    }
    __syncthreads();
    const int r = l >> 2;
    const int c = (l & 3) * 16;
    const us8 v0 = *(const us8*)&Olds[w][r][c];
    const us8 v1 = *(const us8*)&Olds[w][r][c + 8];
    unsigned short* ob = Ob + (size_t)(b * SEQ + qt * 64 + w * 16 + r) * DMODEL + h * DKH + c;
    *(us8*)ob = v0;
    *(us8*)(ob + 8) = v1;
  };

  // one k-tile: QK^T -> online softmax -> in-lane P pack -> K=16 PV.
  // domask is ALWAYS a literal at call sites -> constant-folded.
  auto ITER = [&](int cur, int kb0, bf16x8 qf0, bf16x8 qf1, int qsel, bool domask) {
    const unsigned short* lkb = &kv[cur][0][0] + q15 * 64;
    const unsigned short* lvb = &kv[cur][1][0] + q15 * 64;

    float sp[4][4];
    float mt = -1e30f;
#pragma unroll
    for (int blk = 0; blk < 4; ++blk) {
      const bf16x8 kf0 = *(const bf16x8*)(lkb + blk * 1024 + oc0);
      const bf16x8 kf1 = *(const bf16x8*)(lkb + blk * 1024 + oc1);
      f32x4 c = zf;
      c = __builtin_amdgcn_mfma_f32_16x16x32_bf16(kf0, qf0, c, 0, 0, 0);
      c = __builtin_amdgcn_mfma_f32_16x16x32_bf16(kf1, qf1, c, 0, 0, 0);
#pragma unroll
      for (int r = 0; r < 4; ++r) {
        float s = c[r];  // already in exp2 domain (Q pre-scaled)
        if (domask && (kb0 + blk * 16 + g * 4 + r > qsel)) s = -1e30f;
        sp[blk][r] = s;
        mt = fmaxf(mt, s);
      }
    }
    mt = fmaxf(mt, __shfl_xor(mt, 16));
    mt = fmaxf(mt, __shfl_xor(mt, 32));

    const bool defer = __all(mt - mrun <= 8.0f);
    float mnew, alpha;
    if (defer) { mnew = mrun; alpha = 1.0f; }
    else { mnew = fmaxf(mrun, mt); alpha = fexp2(mrun - mnew); }

    float rs = 0.f;
#pragma unroll
    for (int blk = 0; blk < 4; ++blk)
#pragma unroll
      for (int r = 0; r < 4; ++r) {
        const float p = fexp2(sp[blk][r] - mnew);
        sp[blk][r] = p;
        rs += p;
      }
    if (defer) {
      lrun += rs;                 // per-lane partial; cross-lane reduce at STORE
    } else {
      lrun = lrun * alpha + rs;
      mrun = mnew;
#pragma unroll
      for (int d = 0; d < 4; ++d) ot[d] *= alpha;
    }

    // P -> bf16 K=16 B-fragments in-lane (no shuffles): pfb[blk] holds
    // P[k=kb0+blk*16+4g+i][q15], i=0..3 — exactly the 16x16x16 B layout.
    short4v pfb[4];
#pragma unroll
    for (int blk = 0; blk < 4; ++blk) {
      union { __bf16 hh[4]; short4v v; } pk;
      pk.hh[0] = (__bf16)sp[blk][0];
      pk.hh[1] = (__bf16)sp[blk][1];
      pk.hh[2] = (__bf16)sp[blk][2];
      pk.hh[3] = (__bf16)sp[blk][3];
      pfb[blk] = pk.v;
    }

    // O^T[dt][q] += sum_blk Vt[16dt+q15][k(blk)] * P[k(blk)][q]  (K=16 MFMAs)
    __builtin_amdgcn_s_setprio(1);
#pragma unroll
    for (int dt = 0; dt < 4; ++dt) {
      const unsigned short* vrow = lvb + dt * 1024;
      f32x4 o = ot[dt];
#pragma unroll
      for (int blk = 0; blk < 4; ++blk) {
        const short4v vf = *(const short4v*)(vrow + vc[blk]);
        o = __builtin_amdgcn_mfma_f32_16x16x16bf16_1k(vf, pfb[blk], o, 0, 0, 0);
      }
      ot[dt] = o;
    }
    __builtin_amdgcn_s_setprio(0);
  };

  STAGE(0, 0);
  __syncthreads();
  int cur = 0;

  // ---- phase A main (no mask) ----
  for (int i = 0; i < tA; ++i) {
    STAGE(cur ^ 1, (i + 1) * 64);
    ITER(cur, i * 64, qA0, qA1, qselA, false);
    __syncthreads();
    cur ^= 1;
  }
  // ---- phase A diagonal (mask) + prefetch phase-B tile 0 ----
  STAGE(cur ^ 1, 0);
  ITER(cur, tA * 64, qA0, qA1, qselA, true);
  STORE(tA);
  mrun = -1e30f; lrun = 0.f;
#pragma unroll
  for (int d = 0; d < 4; ++d) ot[d] = zf;
  __syncthreads();
  cur ^= 1;

  // ---- phase B main (no mask) ----
  for (int i = 0; i < tB; ++i) {
    STAGE(cur ^ 1, (i + 1) * 64);
    ITER(cur, i * 64, qB0, qB1, qselB, false);
    __syncthreads();
    cur ^= 1;
  }
  // ---- phase B diagonal (mask) ----
  ITER(cur, tB * 64, qB0, qB1, qselB, true);
  STORE(tB);
}

// ---------------- launch ----------------
extern "C" void kernel_launch(void* const* d_in, const int* in_sizes, int n_in,
                              void* d_out, int out_size, void* d_ws, size_t ws_size,
                              hipStream_t stream) {
  const float* X = (const float*)d_in[0];
  const int* pos = (const int*)d_in[1];
  const float* Wqkv = (const float*)d_in[2];
  const float* Wout = (const float*)d_in[3];
  char* ws = (char*)d_ws;
  unsigned short* xbf    = (unsigned short*)(ws + OFF_XBF);
  unsigned short* wqkvbf = (unsigned short*)(ws + OFF_WQKV);
  unsigned short* woutbf = (unsigned short*)(ws + OFF_WOUT);
  unsigned short* qb     = (unsigned short*)(ws + OFF_Q);
  unsigned short* kbuf   = (unsigned short*)(ws + OFF_K);
  unsigned short* vt     = (unsigned short*)(ws + OFF_VT);
  unsigned short* ob     = (unsigned short*)(ws + OFF_O);
  float2* rope           = (float2*)(ws + OFF_ROPE);

  prep_kernel<<<8192, 256, 0, stream>>>(X, Wqkv, Wout, pos, xbf, wqkvbf, woutbf, rope);
  gemm_kernel<0><<<dim3(NQKV / 128, MTOT / 128), 256, 0, stream>>>(
      xbf, wqkvbf, qb, kbuf, vt, rope, nullptr);
  attn_kernel<<<dim3(16, 32), 256, 0, stream>>>(qb, kbuf, vt, ob);
  gemm_kernel<1><<<dim3(DMODEL / 128, MTOT / 128), 256, 0, stream>>>(
      ob, woutbf, nullptr, nullptr, nullptr, nullptr, (float*)d_out);
}